// Round 1
// baseline (4429.390 us; speedup 1.0000x reference)
//
#include <hip/hip_runtime.h>

#define CIN 64
#define COUT 128
#define NPB 16          // nodes per block in transform kernels
constexpr float LN_EPS = 1e-5f;

// ---------------- scatter: agg[dst] += x[src], C=64 (float4 per thread, 16 thr/edge)
__global__ __launch_bounds__(256) void scatter_c64(
    const float* __restrict__ x, const int* __restrict__ src,
    const int* __restrict__ dst, float* __restrict__ agg, int n_edges)
{
    int t = blockIdx.x * blockDim.x + threadIdx.x;
    int e = t >> 4;
    if (e >= n_edges) return;
    int q = (t & 15) << 2;
    int s = src[e], d = dst[e];
    const float4 v = *reinterpret_cast<const float4*>(x + (size_t)s * CIN + q);
    float* a = agg + (size_t)d * CIN + q;
    atomicAdd(a + 0, v.x);
    atomicAdd(a + 1, v.y);
    atomicAdd(a + 2, v.z);
    atomicAdd(a + 3, v.w);
}

// ---------------- scatter: agg[dst] += y[src], C=128 (float4 per thread, 32 thr/edge)
__global__ __launch_bounds__(256) void scatter_c128(
    const float* __restrict__ y, const int* __restrict__ src,
    const int* __restrict__ dst, float* __restrict__ agg, int n_edges)
{
    int t = blockIdx.x * blockDim.x + threadIdx.x;
    int e = t >> 5;
    if (e >= n_edges) return;
    int q = (t & 31) << 2;
    int s = src[e], d = dst[e];
    const float4 v = *reinterpret_cast<const float4*>(y + (size_t)s * COUT + q);
    float* a = agg + (size_t)d * COUT + q;
    atomicAdd(a + 0, v.x);
    atomicAdd(a + 1, v.y);
    atomicAdd(a + 2, v.z);
    atomicAdd(a + 3, v.w);
}

// ---------------- conv0: y = relu(LN(x@wr + agg@wn + b))  (K=64 -> 128 ch)
__global__ __launch_bounds__(128) void conv0_ln_relu(
    const float* __restrict__ x, const float* __restrict__ agg,
    const float* __restrict__ wr, const float* __restrict__ wn,
    const float* __restrict__ b, const float* __restrict__ gamma,
    const float* __restrict__ beta, float* __restrict__ y, int n_nodes)
{
    __shared__ float sx[NPB * CIN];
    __shared__ float sa[NPB * CIN];
    __shared__ float2 sred[2][NPB];

    const int c = threadIdx.x;                 // output channel 0..127
    const int node0 = blockIdx.x * NPB;
    const int rows = min(NPB, n_nodes - node0);

    for (int idx = c; idx < rows * CIN; idx += 128) {
        sx[idx] = x[(size_t)node0 * CIN + idx];
        sa[idx] = agg[(size_t)node0 * CIN + idx];
    }
    __syncthreads();

    const float bc = b[c], gc = gamma[c], bec = beta[c];
    float acc[NPB];
#pragma unroll
    for (int n = 0; n < NPB; n++) acc[n] = bc;

    for (int k = 0; k < CIN; k += 4) {
        const float wr0 = wr[(k + 0) * COUT + c];
        const float wr1 = wr[(k + 1) * COUT + c];
        const float wr2 = wr[(k + 2) * COUT + c];
        const float wr3 = wr[(k + 3) * COUT + c];
        const float wn0 = wn[(k + 0) * COUT + c];
        const float wn1 = wn[(k + 1) * COUT + c];
        const float wn2 = wn[(k + 2) * COUT + c];
        const float wn3 = wn[(k + 3) * COUT + c];
#pragma unroll
        for (int n = 0; n < NPB; n++) {
            const float4 xv = *reinterpret_cast<const float4*>(&sx[n * CIN + k]);
            const float4 av = *reinterpret_cast<const float4*>(&sa[n * CIN + k]);
            acc[n] += xv.x * wr0 + xv.y * wr1 + xv.z * wr2 + xv.w * wr3
                    + av.x * wn0 + av.y * wn1 + av.z * wn2 + av.w * wn3;
        }
    }

    // LayerNorm across the 128 channels (2 waves)
    const int lane = c & 63, wid = c >> 6;
#pragma unroll
    for (int n = 0; n < NPB; n++) {
        float s = acc[n], s2 = acc[n] * acc[n];
        for (int off = 32; off; off >>= 1) {
            s  += __shfl_xor(s, off);
            s2 += __shfl_xor(s2, off);
        }
        if (lane == 0) sred[wid][n] = make_float2(s, s2);
    }
    __syncthreads();
#pragma unroll
    for (int n = 0; n < NPB; n++) {
        if (n >= rows) break;
        const float2 t0 = sred[0][n], t1 = sred[1][n];
        const float mu  = (t0.x + t1.x) * (1.0f / COUT);
        const float var = (t0.y + t1.y) * (1.0f / COUT) - mu * mu;
        const float r = rsqrtf(var + LN_EPS);
        const float v = (acc[n] - mu) * r * gc + bec;
        y[((size_t)node0 + n) * COUT + c] = fmaxf(v, 0.0f);
    }
}

// ---------------- conv1 + residual: out = relu(LN(y@wr1 + agg@wn1 + b1 + x@wl + bl))
__global__ __launch_bounds__(128) void conv1_res_ln_relu(
    const float* __restrict__ y, const float* __restrict__ agg,
    const float* __restrict__ x,
    const float* __restrict__ wr, const float* __restrict__ wn,
    const float* __restrict__ wl,
    const float* __restrict__ b, const float* __restrict__ bl,
    const float* __restrict__ gamma, const float* __restrict__ beta,
    float* __restrict__ out, int n_nodes)
{
    __shared__ float sy[NPB * COUT];
    __shared__ float sa[NPB * COUT];
    __shared__ float sx[NPB * CIN];
    __shared__ float2 sred[2][NPB];

    const int c = threadIdx.x;
    const int node0 = blockIdx.x * NPB;
    const int rows = min(NPB, n_nodes - node0);

    for (int idx = c; idx < rows * COUT; idx += 128) {
        sy[idx] = y[(size_t)node0 * COUT + idx];
        sa[idx] = agg[(size_t)node0 * COUT + idx];
    }
    for (int idx = c; idx < rows * CIN; idx += 128) {
        sx[idx] = x[(size_t)node0 * CIN + idx];
    }
    __syncthreads();

    const float bc = b[c] + bl[c], gc = gamma[c], bec = beta[c];
    float acc[NPB];
#pragma unroll
    for (int n = 0; n < NPB; n++) acc[n] = bc;

    for (int k = 0; k < COUT; k += 4) {
        const float wr0 = wr[(k + 0) * COUT + c];
        const float wr1 = wr[(k + 1) * COUT + c];
        const float wr2 = wr[(k + 2) * COUT + c];
        const float wr3 = wr[(k + 3) * COUT + c];
        const float wn0 = wn[(k + 0) * COUT + c];
        const float wn1 = wn[(k + 1) * COUT + c];
        const float wn2 = wn[(k + 2) * COUT + c];
        const float wn3 = wn[(k + 3) * COUT + c];
#pragma unroll
        for (int n = 0; n < NPB; n++) {
            const float4 yv = *reinterpret_cast<const float4*>(&sy[n * COUT + k]);
            const float4 av = *reinterpret_cast<const float4*>(&sa[n * COUT + k]);
            acc[n] += yv.x * wr0 + yv.y * wr1 + yv.z * wr2 + yv.w * wr3
                    + av.x * wn0 + av.y * wn1 + av.z * wn2 + av.w * wn3;
        }
    }
    for (int k = 0; k < CIN; k += 4) {
        const float wl0 = wl[(k + 0) * COUT + c];
        const float wl1 = wl[(k + 1) * COUT + c];
        const float wl2 = wl[(k + 2) * COUT + c];
        const float wl3 = wl[(k + 3) * COUT + c];
#pragma unroll
        for (int n = 0; n < NPB; n++) {
            const float4 xv = *reinterpret_cast<const float4*>(&sx[n * CIN + k]);
            acc[n] += xv.x * wl0 + xv.y * wl1 + xv.z * wl2 + xv.w * wl3;
        }
    }

    const int lane = c & 63, wid = c >> 6;
#pragma unroll
    for (int n = 0; n < NPB; n++) {
        float s = acc[n], s2 = acc[n] * acc[n];
        for (int off = 32; off; off >>= 1) {
            s  += __shfl_xor(s, off);
            s2 += __shfl_xor(s2, off);
        }
        if (lane == 0) sred[wid][n] = make_float2(s, s2);
    }
    __syncthreads();
#pragma unroll
    for (int n = 0; n < NPB; n++) {
        if (n >= rows) break;
        const float2 t0 = sred[0][n], t1 = sred[1][n];
        const float mu  = (t0.x + t1.x) * (1.0f / COUT);
        const float var = (t0.y + t1.y) * (1.0f / COUT) - mu * mu;
        const float r = rsqrtf(var + LN_EPS);
        const float v = (acc[n] - mu) * r * gc + bec;
        out[((size_t)node0 + n) * COUT + c] = fmaxf(v, 0.0f);
    }
}

extern "C" void kernel_launch(void* const* d_in, const int* in_sizes, int n_in,
                              void* d_out, int out_size, void* d_ws, size_t ws_size,
                              hipStream_t stream)
{
    const float* x       = (const float*)d_in[0];
    const int*   ei      = (const int*)d_in[1];
    const float* w_root0 = (const float*)d_in[2];
    const float* w_nbr0  = (const float*)d_in[3];
    const float* b0      = (const float*)d_in[4];
    const float* w_root1 = (const float*)d_in[5];
    const float* w_nbr1  = (const float*)d_in[6];
    const float* b1      = (const float*)d_in[7];
    const float* gamma0  = (const float*)d_in[8];
    const float* beta0   = (const float*)d_in[9];
    const float* gamma1  = (const float*)d_in[10];
    const float* beta1   = (const float*)d_in[11];
    const float* w_lin   = (const float*)d_in[12];
    const float* b_lin   = (const float*)d_in[13];
    float* out = (float*)d_out;

    const int n_nodes = in_sizes[0] / CIN;   // 100000
    const int n_edges = in_sizes[1] / 2;     // 1600000
    const int* src = ei;
    const int* dst = ei + n_edges;

    char* ws = (char*)d_ws;
    float* ybuf   = (float*)ws;                                    // n_nodes*COUT f32
    float* aggbuf = (float*)(ws + (size_t)n_nodes * COUT * 4);     // n_nodes*COUT f32

    const int nblk = (n_nodes + NPB - 1) / NPB;

    // ---- GraphConv 0
    hipMemsetAsync(aggbuf, 0, (size_t)n_nodes * CIN * sizeof(float), stream);
    {
        long long thr = (long long)n_edges * 16;
        scatter_c64<<<(int)((thr + 255) / 256), 256, 0, stream>>>(x, src, dst, aggbuf, n_edges);
    }
    conv0_ln_relu<<<nblk, 128, 0, stream>>>(x, aggbuf, w_root0, w_nbr0, b0,
                                            gamma0, beta0, ybuf, n_nodes);

    // ---- GraphConv 1 + residual
    hipMemsetAsync(aggbuf, 0, (size_t)n_nodes * COUT * sizeof(float), stream);
    {
        long long thr = (long long)n_edges * 32;
        scatter_c128<<<(int)((thr + 255) / 256), 256, 0, stream>>>(ybuf, src, dst, aggbuf, n_edges);
    }
    conv1_res_ln_relu<<<nblk, 128, 0, stream>>>(ybuf, aggbuf, x, w_root1, w_nbr1, w_lin,
                                                b1, b_lin, gamma1, beta1, out, n_nodes);
}

// Round 2
// 977.573 us; speedup vs baseline: 4.5310x; 4.5310x over previous
//
#include <hip/hip_runtime.h>

#define CIN 64
#define COUT 128
#define NPB 16          // nodes per block in transform kernels
#define SCANB 1024
constexpr float LN_EPS = 1e-5f;

// ================= CSR build =================

__global__ __launch_bounds__(256) void hist_kernel(
    const int* __restrict__ dst, int* __restrict__ deg, int n_edges)
{
    int e = blockIdx.x * blockDim.x + threadIdx.x;
    if (e < n_edges) atomicAdd(&deg[dst[e]], 1);
}

// block-local exclusive scan of deg -> rowptr, block totals -> chunk_sums
__global__ __launch_bounds__(SCANB) void scan1_kernel(
    const int* __restrict__ deg, int* __restrict__ rowptr,
    int* __restrict__ chunk_sums, int n)
{
    __shared__ int s[SCANB];
    const int t = threadIdx.x;
    const int i = blockIdx.x * SCANB + t;
    const int v = (i < n) ? deg[i] : 0;
    s[t] = v;
    __syncthreads();
#pragma unroll
    for (int off = 1; off < SCANB; off <<= 1) {
        int add = (t >= off) ? s[t - off] : 0;
        __syncthreads();
        s[t] += add;
        __syncthreads();
    }
    if (i < n) rowptr[i] = s[t] - v;          // exclusive, chunk-local
    if (t == SCANB - 1) chunk_sums[blockIdx.x] = s[t];
}

// exclusive scan of chunk_sums (nc <= SCANB) -> chunk_off
__global__ __launch_bounds__(SCANB) void scan2_kernel(
    const int* __restrict__ chunk_sums, int* __restrict__ chunk_off, int nc)
{
    __shared__ int s[SCANB];
    const int t = threadIdx.x;
    const int v = (t < nc) ? chunk_sums[t] : 0;
    s[t] = v;
    __syncthreads();
#pragma unroll
    for (int off = 1; off < SCANB; off <<= 1) {
        int add = (t >= off) ? s[t - off] : 0;
        __syncthreads();
        s[t] += add;
        __syncthreads();
    }
    if (t < nc) chunk_off[t] = s[t] - v;
}

__global__ __launch_bounds__(SCANB) void scan3_kernel(
    int* __restrict__ rowptr, const int* __restrict__ chunk_off,
    int n, int n_edges)
{
    const int i = blockIdx.x * SCANB + threadIdx.x;
    if (i < n) rowptr[i] += chunk_off[blockIdx.x];
    if (i == 0) rowptr[n] = n_edges;
}

__global__ __launch_bounds__(256) void fill_kernel(
    const int* __restrict__ src, const int* __restrict__ dst,
    int* __restrict__ cursor, int* __restrict__ esorted, int n_edges)
{
    int e = blockIdx.x * blockDim.x + threadIdx.x;
    if (e >= n_edges) return;
    int pos = atomicAdd(&cursor[dst[e]], 1);
    esorted[pos] = src[e];
}

// ================= gathers (no atomics) =================

// 4 nodes per 256-thread block; one wave per node, thread c = channel
__global__ __launch_bounds__(256) void gather_c64(
    const float* __restrict__ x, const int* __restrict__ rowptr,
    const int* __restrict__ es, float* __restrict__ agg, int n_nodes)
{
    const int node = blockIdx.x * 4 + (threadIdx.x >> 6);
    if (node >= n_nodes) return;
    const int c = threadIdx.x & 63;
    const int s0 = rowptr[node], s1 = rowptr[node + 1];
    float acc = 0.0f;
    for (int e = s0; e < s1; e++)
        acc += x[(size_t)es[e] * CIN + c];
    agg[(size_t)node * CIN + c] = acc;
}

// 2 nodes per 256-thread block; 128 threads per node (wave-uniform node)
__global__ __launch_bounds__(256) void gather_c128(
    const float* __restrict__ y, const int* __restrict__ rowptr,
    const int* __restrict__ es, float* __restrict__ agg, int n_nodes)
{
    const int node = blockIdx.x * 2 + (threadIdx.x >> 7);
    if (node >= n_nodes) return;
    const int c = threadIdx.x & 127;
    const int s0 = rowptr[node], s1 = rowptr[node + 1];
    float acc = 0.0f;
    for (int e = s0; e < s1; e++)
        acc += y[(size_t)es[e] * COUT + c];
    agg[(size_t)node * COUT + c] = acc;
}

// ================= fused transforms =================

__global__ __launch_bounds__(128) void conv0_ln_relu(
    const float* __restrict__ x, const float* __restrict__ agg,
    const float* __restrict__ wr, const float* __restrict__ wn,
    const float* __restrict__ b, const float* __restrict__ gamma,
    const float* __restrict__ beta, float* __restrict__ y, int n_nodes)
{
    __shared__ float sx[NPB * CIN];
    __shared__ float sa[NPB * CIN];
    __shared__ float2 sred[2][NPB];

    const int c = threadIdx.x;                 // output channel 0..127
    const int node0 = blockIdx.x * NPB;
    const int rows = min(NPB, n_nodes - node0);

    for (int idx = c; idx < rows * CIN; idx += 128) {
        sx[idx] = x[(size_t)node0 * CIN + idx];
        sa[idx] = agg[(size_t)node0 * CIN + idx];
    }
    __syncthreads();

    const float bc = b[c], gc = gamma[c], bec = beta[c];
    float acc[NPB];
#pragma unroll
    for (int n = 0; n < NPB; n++) acc[n] = bc;

    for (int k = 0; k < CIN; k += 4) {
        const float wr0 = wr[(k + 0) * COUT + c];
        const float wr1 = wr[(k + 1) * COUT + c];
        const float wr2 = wr[(k + 2) * COUT + c];
        const float wr3 = wr[(k + 3) * COUT + c];
        const float wn0 = wn[(k + 0) * COUT + c];
        const float wn1 = wn[(k + 1) * COUT + c];
        const float wn2 = wn[(k + 2) * COUT + c];
        const float wn3 = wn[(k + 3) * COUT + c];
#pragma unroll
        for (int n = 0; n < NPB; n++) {
            const float4 xv = *reinterpret_cast<const float4*>(&sx[n * CIN + k]);
            const float4 av = *reinterpret_cast<const float4*>(&sa[n * CIN + k]);
            acc[n] += xv.x * wr0 + xv.y * wr1 + xv.z * wr2 + xv.w * wr3
                    + av.x * wn0 + av.y * wn1 + av.z * wn2 + av.w * wn3;
        }
    }

    const int lane = c & 63, wid = c >> 6;
#pragma unroll
    for (int n = 0; n < NPB; n++) {
        float s = acc[n], s2 = acc[n] * acc[n];
        for (int off = 32; off; off >>= 1) {
            s  += __shfl_xor(s, off);
            s2 += __shfl_xor(s2, off);
        }
        if (lane == 0) sred[wid][n] = make_float2(s, s2);
    }
    __syncthreads();
#pragma unroll
    for (int n = 0; n < NPB; n++) {
        if (n >= rows) break;
        const float2 t0 = sred[0][n], t1 = sred[1][n];
        const float mu  = (t0.x + t1.x) * (1.0f / COUT);
        const float var = (t0.y + t1.y) * (1.0f / COUT) - mu * mu;
        const float r = rsqrtf(var + LN_EPS);
        const float v = (acc[n] - mu) * r * gc + bec;
        y[((size_t)node0 + n) * COUT + c] = fmaxf(v, 0.0f);
    }
}

__global__ __launch_bounds__(128) void conv1_res_ln_relu(
    const float* __restrict__ y, const float* __restrict__ agg,
    const float* __restrict__ x,
    const float* __restrict__ wr, const float* __restrict__ wn,
    const float* __restrict__ wl,
    const float* __restrict__ b, const float* __restrict__ bl,
    const float* __restrict__ gamma, const float* __restrict__ beta,
    float* __restrict__ out, int n_nodes)
{
    __shared__ float sy[NPB * COUT];
    __shared__ float sa[NPB * COUT];
    __shared__ float sx[NPB * CIN];
    __shared__ float2 sred[2][NPB];

    const int c = threadIdx.x;
    const int node0 = blockIdx.x * NPB;
    const int rows = min(NPB, n_nodes - node0);

    for (int idx = c; idx < rows * COUT; idx += 128) {
        sy[idx] = y[(size_t)node0 * COUT + idx];
        sa[idx] = agg[(size_t)node0 * COUT + idx];
    }
    for (int idx = c; idx < rows * CIN; idx += 128) {
        sx[idx] = x[(size_t)node0 * CIN + idx];
    }
    __syncthreads();

    const float bc = b[c] + bl[c], gc = gamma[c], bec = beta[c];
    float acc[NPB];
#pragma unroll
    for (int n = 0; n < NPB; n++) acc[n] = bc;

    for (int k = 0; k < COUT; k += 4) {
        const float wr0 = wr[(k + 0) * COUT + c];
        const float wr1 = wr[(k + 1) * COUT + c];
        const float wr2 = wr[(k + 2) * COUT + c];
        const float wr3 = wr[(k + 3) * COUT + c];
        const float wn0 = wn[(k + 0) * COUT + c];
        const float wn1 = wn[(k + 1) * COUT + c];
        const float wn2 = wn[(k + 2) * COUT + c];
        const float wn3 = wn[(k + 3) * COUT + c];
#pragma unroll
        for (int n = 0; n < NPB; n++) {
            const float4 yv = *reinterpret_cast<const float4*>(&sy[n * COUT + k]);
            const float4 av = *reinterpret_cast<const float4*>(&sa[n * COUT + k]);
            acc[n] += yv.x * wr0 + yv.y * wr1 + yv.z * wr2 + yv.w * wr3
                    + av.x * wn0 + av.y * wn1 + av.z * wn2 + av.w * wn3;
        }
    }
    for (int k = 0; k < CIN; k += 4) {
        const float wl0 = wl[(k + 0) * COUT + c];
        const float wl1 = wl[(k + 1) * COUT + c];
        const float wl2 = wl[(k + 2) * COUT + c];
        const float wl3 = wl[(k + 3) * COUT + c];
#pragma unroll
        for (int n = 0; n < NPB; n++) {
            const float4 xv = *reinterpret_cast<const float4*>(&sx[n * CIN + k]);
            acc[n] += xv.x * wl0 + xv.y * wl1 + xv.z * wl2 + xv.w * wl3;
        }
    }

    const int lane = c & 63, wid = c >> 6;
#pragma unroll
    for (int n = 0; n < NPB; n++) {
        float s = acc[n], s2 = acc[n] * acc[n];
        for (int off = 32; off; off >>= 1) {
            s  += __shfl_xor(s, off);
            s2 += __shfl_xor(s2, off);
        }
        if (lane == 0) sred[wid][n] = make_float2(s, s2);
    }
    __syncthreads();
#pragma unroll
    for (int n = 0; n < NPB; n++) {
        if (n >= rows) break;
        const float2 t0 = sred[0][n], t1 = sred[1][n];
        const float mu  = (t0.x + t1.x) * (1.0f / COUT);
        const float var = (t0.y + t1.y) * (1.0f / COUT) - mu * mu;
        const float r = rsqrtf(var + LN_EPS);
        const float v = (acc[n] - mu) * r * gc + bec;
        out[((size_t)node0 + n) * COUT + c] = fmaxf(v, 0.0f);
    }
}

extern "C" void kernel_launch(void* const* d_in, const int* in_sizes, int n_in,
                              void* d_out, int out_size, void* d_ws, size_t ws_size,
                              hipStream_t stream)
{
    const float* x       = (const float*)d_in[0];
    const int*   ei      = (const int*)d_in[1];
    const float* w_root0 = (const float*)d_in[2];
    const float* w_nbr0  = (const float*)d_in[3];
    const float* b0      = (const float*)d_in[4];
    const float* w_root1 = (const float*)d_in[5];
    const float* w_nbr1  = (const float*)d_in[6];
    const float* b1      = (const float*)d_in[7];
    const float* gamma0  = (const float*)d_in[8];
    const float* beta0   = (const float*)d_in[9];
    const float* gamma1  = (const float*)d_in[10];
    const float* beta1   = (const float*)d_in[11];
    const float* w_lin   = (const float*)d_in[12];
    const float* b_lin   = (const float*)d_in[13];
    float* out = (float*)d_out;

    const int n_nodes = in_sizes[0] / CIN;   // 100000
    const int n_edges = in_sizes[1] / 2;     // 1600000
    const int* src = ei;
    const int* dst = ei + n_edges;

    // ---- workspace layout ----
    char* ws = (char*)d_ws;
    float* ybuf   = (float*)ws;                                       // n*COUT f32
    float* aggbuf = (float*)(ws + (size_t)n_nodes * COUT * 4);        // n*COUT f32
    int*   rowptr = (int*)(ws + (size_t)n_nodes * COUT * 8);          // n+1
    int*   cursor = rowptr + (n_nodes + 1);                           // n (deg, then cursor)
    int*   csum   = cursor + n_nodes;                                 // <=1024
    int*   coff   = csum + SCANB;                                     // <=1024
    int*   esorted= coff + SCANB;                                     // n_edges

    const int nchunks = (n_nodes + SCANB - 1) / SCANB;
    const int eblk = (n_edges + 255) / 256;
    const int nblk = (n_nodes + NPB - 1) / NPB;

    // ---- CSR build (once per call, reused by both convs) ----
    hipMemsetAsync(cursor, 0, (size_t)n_nodes * sizeof(int), stream);
    hist_kernel<<<eblk, 256, 0, stream>>>(dst, cursor, n_edges);
    scan1_kernel<<<nchunks, SCANB, 0, stream>>>(cursor, rowptr, csum, n_nodes);
    scan2_kernel<<<1, SCANB, 0, stream>>>(csum, coff, nchunks);
    scan3_kernel<<<nchunks, SCANB, 0, stream>>>(rowptr, coff, n_nodes, n_edges);
    hipMemcpyAsync(cursor, rowptr, (size_t)n_nodes * sizeof(int),
                   hipMemcpyDeviceToDevice, stream);
    fill_kernel<<<eblk, 256, 0, stream>>>(src, dst, cursor, esorted, n_edges);

    // ---- GraphConv 0 ----
    gather_c64<<<(n_nodes + 3) / 4, 256, 0, stream>>>(x, rowptr, esorted, aggbuf, n_nodes);
    conv0_ln_relu<<<nblk, 128, 0, stream>>>(x, aggbuf, w_root0, w_nbr0, b0,
                                            gamma0, beta0, ybuf, n_nodes);

    // ---- GraphConv 1 + residual ----
    gather_c128<<<(n_nodes + 1) / 2, 256, 0, stream>>>(ybuf, rowptr, esorted, aggbuf, n_nodes);
    conv1_res_ln_relu<<<nblk, 128, 0, stream>>>(ybuf, aggbuf, x, w_root1, w_nbr1, w_lin,
                                                b1, b_lin, gamma1, beta1, out, n_nodes);
}

// Round 3
// 522.971 us; speedup vs baseline: 8.4697x; 1.8693x over previous
//
#include <hip/hip_runtime.h>

#define CIN 64
#define COUT 128
#define SCANB 1024
constexpr float LN_EPS = 1e-5f;

typedef __attribute__((ext_vector_type(8))) short    bf16x8;
typedef __attribute__((ext_vector_type(4))) float    f32x4;
typedef __attribute__((ext_vector_type(8))) unsigned short us8;

__device__ inline float b2f(unsigned short u) {
    union { unsigned int i; float f; } v; v.i = ((unsigned int)u) << 16; return v.f;
}
__device__ inline unsigned short f2b(float f) {
    union { float f; unsigned int i; } v; v.f = f;
    unsigned int x = v.i;
    return (unsigned short)((x + 0x7FFFu + ((x >> 16) & 1u)) >> 16);
}

// ================= CSR build =================

__global__ __launch_bounds__(256) void hist_kernel(
    const int* __restrict__ dst, int* __restrict__ deg, int n_edges)
{
    int e = blockIdx.x * blockDim.x + threadIdx.x;
    if (e < n_edges) atomicAdd(&deg[dst[e]], 1);
}

__global__ __launch_bounds__(SCANB) void scan1_kernel(
    const int* __restrict__ deg, int* __restrict__ rowptr,
    int* __restrict__ chunk_sums, int n)
{
    __shared__ int s[SCANB];
    const int t = threadIdx.x;
    const int i = blockIdx.x * SCANB + t;
    const int v = (i < n) ? deg[i] : 0;
    s[t] = v;
    __syncthreads();
#pragma unroll
    for (int off = 1; off < SCANB; off <<= 1) {
        int add = (t >= off) ? s[t - off] : 0;
        __syncthreads();
        s[t] += add;
        __syncthreads();
    }
    if (i < n) rowptr[i] = s[t] - v;
    if (t == SCANB - 1) chunk_sums[blockIdx.x] = s[t];
}

__global__ __launch_bounds__(SCANB) void scan2_kernel(
    const int* __restrict__ chunk_sums, int* __restrict__ chunk_off, int nc)
{
    __shared__ int s[SCANB];
    const int t = threadIdx.x;
    const int v = (t < nc) ? chunk_sums[t] : 0;
    s[t] = v;
    __syncthreads();
#pragma unroll
    for (int off = 1; off < SCANB; off <<= 1) {
        int add = (t >= off) ? s[t - off] : 0;
        __syncthreads();
        s[t] += add;
        __syncthreads();
    }
    if (t < nc) chunk_off[t] = s[t] - v;
}

__global__ __launch_bounds__(SCANB) void scan3_kernel(
    int* __restrict__ rowptr, const int* __restrict__ chunk_off,
    int n, int n_edges)
{
    const int i = blockIdx.x * SCANB + threadIdx.x;
    if (i < n) rowptr[i] += chunk_off[blockIdx.x];
    if (i == 0) rowptr[n] = n_edges;
}

__global__ __launch_bounds__(256) void fill_kernel(
    const int* __restrict__ src, const int* __restrict__ dst,
    int* __restrict__ cursor, int* __restrict__ esorted, int n_edges)
{
    int e = blockIdx.x * blockDim.x + threadIdx.x;
    if (e >= n_edges) return;
    int pos = atomicAdd(&cursor[dst[e]], 1);
    esorted[pos] = src[e];
}

// ================= prep: weights -> bf16 transposed, x -> bf16 =================

// wt0[n][k], k in [0,128): k<64 -> w_root0[k][n], else w_nbr0[k-64][n]
// wt1[n][k], k in [0,320): k<128 -> w_root1, <256 -> w_nbr1, else w_lin
__global__ __launch_bounds__(256) void prep_weights(
    const float* __restrict__ wr0, const float* __restrict__ wn0,
    const float* __restrict__ wr1, const float* __restrict__ wn1,
    const float* __restrict__ wl,
    unsigned short* __restrict__ wt0, unsigned short* __restrict__ wt1)
{
    int t = blockIdx.x * blockDim.x + threadIdx.x;
    if (t < 128 * 128) {
        int n = t >> 7, k = t & 127;
        float v = (k < 64) ? wr0[k * COUT + n] : wn0[(k - 64) * COUT + n];
        wt0[n * 128 + k] = f2b(v);
    } else {
        int t2 = t - 128 * 128;
        if (t2 >= 128 * 320) return;
        int n = t2 / 320, k = t2 % 320;
        float v;
        if (k < 128)      v = wr1[k * COUT + n];
        else if (k < 256) v = wn1[(k - 128) * COUT + n];
        else              v = wl[(k - 256) * COUT + n];
        wt1[n * 320 + k] = f2b(v);
    }
}

// x (f32 [n][64]) -> ab0[:,0:64] and a1[:,256:320] as bf16
__global__ __launch_bounds__(256) void convert_x(
    const float* __restrict__ x, unsigned short* __restrict__ ab0,
    unsigned short* __restrict__ a1, int n_nodes)
{
    int t = blockIdx.x * blockDim.x + threadIdx.x;
    int node = t >> 4;
    if (node >= n_nodes) return;
    int c = (t & 15) << 2;
    const float4 v = *reinterpret_cast<const float4*>(x + (size_t)node * CIN + c);
    unsigned int lo = (unsigned int)f2b(v.x) | ((unsigned int)f2b(v.y) << 16);
    unsigned int hi = (unsigned int)f2b(v.z) | ((unsigned int)f2b(v.w) << 16);
    unsigned int* p0 = (unsigned int*)(ab0 + (size_t)node * 128 + c);
    p0[0] = lo; p0[1] = hi;
    unsigned int* p1 = (unsigned int*)(a1 + (size_t)node * 320 + 256 + c);
    p1[0] = lo; p1[1] = hi;
}

// ================= gathers (bf16 in/out, f32 accum) =================

// one wave per node; half-waves split edges; lane covers 2 channels (of 64)
__global__ __launch_bounds__(256) void gather_c64(
    unsigned short* __restrict__ ab0, const int* __restrict__ rowptr,
    const int* __restrict__ es, int n_nodes)
{
    const int node = blockIdx.x * 4 + (threadIdx.x >> 6);
    if (node >= n_nodes) return;
    const int l = threadIdx.x & 63;
    const int eh = l >> 5, c2 = (l & 31) << 1;
    const int s0 = rowptr[node], s1 = rowptr[node + 1];
    float a0 = 0.f, a1v = 0.f;
    for (int e = s0 + eh; e < s1; e += 2) {
        const unsigned int v = *(const unsigned int*)(ab0 + (size_t)es[e] * 128 + c2);
        a0  += b2f((unsigned short)v);
        a1v += b2f((unsigned short)(v >> 16));
    }
    a0  += __shfl_xor(a0, 32);
    a1v += __shfl_xor(a1v, 32);
    if (eh == 0) {
        unsigned int packed = (unsigned int)f2b(a0) | ((unsigned int)f2b(a1v) << 16);
        *(unsigned int*)(ab0 + (size_t)node * 128 + 64 + c2) = packed;
    }
}

// one wave per node; lane covers 4 channels (of 128); y rows live in a1[:,0:128]
__global__ __launch_bounds__(256) void gather_c128(
    unsigned short* __restrict__ a1, const int* __restrict__ rowptr,
    const int* __restrict__ es, int n_nodes)
{
    const int node = blockIdx.x * 4 + (threadIdx.x >> 6);
    if (node >= n_nodes) return;
    const int l = threadIdx.x & 63;
    const int eh = l >> 5, c4 = (l & 31) << 2;
    const int s0 = rowptr[node], s1 = rowptr[node + 1];
    float a0 = 0.f, a1v = 0.f, a2 = 0.f, a3 = 0.f;
    for (int e = s0 + eh; e < s1; e += 2) {
        const unsigned short* row = a1 + (size_t)es[e] * 320 + c4;
        const unsigned int v0 = *(const unsigned int*)(row);
        const unsigned int v1 = *(const unsigned int*)(row + 2);
        a0 += b2f((unsigned short)v0); a1v += b2f((unsigned short)(v0 >> 16));
        a2 += b2f((unsigned short)v1); a3  += b2f((unsigned short)(v1 >> 16));
    }
    a0 += __shfl_xor(a0, 32); a1v += __shfl_xor(a1v, 32);
    a2 += __shfl_xor(a2, 32); a3  += __shfl_xor(a3, 32);
    if (eh == 0) {
        unsigned int p0 = (unsigned int)f2b(a0) | ((unsigned int)f2b(a1v) << 16);
        unsigned int p1 = (unsigned int)f2b(a2) | ((unsigned int)f2b(a3) << 16);
        unsigned int* w = (unsigned int*)(a1 + (size_t)node * 320 + 128 + c4);
        w[0] = p0; w[1] = p1;
    }
}

// ================= MFMA convs =================
// D[m][n]: col = lane&15, row = (lane>>4)*4 + reg  (m89-verified)
// a_frag lane l: A[m0 + (l&15)][ks*32 + (l>>4)*8 + j]
// b_frag lane l: Wt[n0 + (l&15)][ks*32 + (l>>4)*8 + j]   (Wt = W^T)

// conv0: y = relu(LN(ab0 @ wt0^T + b0)); write bf16 into a1[:,0:128] (stride 320)
__global__ __launch_bounds__(256) void conv0_mfma(
    const unsigned short* __restrict__ A,  // ab0 [npad][128]
    const unsigned short* __restrict__ Wt, // [128][128]
    const float* __restrict__ b, const float* __restrict__ gamma,
    const float* __restrict__ beta,
    unsigned short* __restrict__ Yout,     // a1 base
    int n_nodes)
{
    __shared__ unsigned short lt[4][16 * 136];
    const int wid = threadIdx.x >> 6;
    const int lane = threadIdx.x & 63;
    const int m0 = blockIdx.x * 64 + wid * 16;
    if (m0 >= n_nodes) return;
    const int g = lane >> 4, fr = lane & 15;

    f32x4 acc[8];
    float gm[8], bt[8];
#pragma unroll
    for (int nt = 0; nt < 8; nt++) {
        const int col = nt * 16 + fr;
        const float bb = b[col];
        acc[nt] = (f32x4){bb, bb, bb, bb};
        gm[nt] = gamma[col]; bt[nt] = beta[col];
    }

    const bf16x8* Ap = reinterpret_cast<const bf16x8*>(A + (size_t)(m0 + fr) * 128) + g;
    const bf16x8* Wp = reinterpret_cast<const bf16x8*>(Wt + (size_t)fr * 128) + g;
#pragma unroll
    for (int ks = 0; ks < 4; ks++) {
        const bf16x8 a = Ap[ks * 4];
#pragma unroll
        for (int nt = 0; nt < 8; nt++) {
            const bf16x8 w = Wp[nt * 16 * 16 + ks * 4];   // nt*16 rows * (128/8)
            acc[nt] = __builtin_amdgcn_mfma_f32_16x16x32_bf16(a, w, acc[nt], 0, 0, 0);
        }
    }

    // LN + ReLU per row (row = g*4 + r), then bf16 into LDS
#pragma unroll
    for (int r = 0; r < 4; r++) {
        float s = 0.f, s2 = 0.f;
#pragma unroll
        for (int nt = 0; nt < 8; nt++) { const float v = acc[nt][r]; s += v; s2 += v * v; }
#pragma unroll
        for (int off = 1; off < 16; off <<= 1) {
            s += __shfl_xor(s, off); s2 += __shfl_xor(s2, off);
        }
        const float mu = s * (1.0f / COUT);
        const float var = s2 * (1.0f / COUT) - mu * mu;
        const float rstd = rsqrtf(var + LN_EPS);
        const int lrow = g * 4 + r;
#pragma unroll
        for (int nt = 0; nt < 8; nt++) {
            const float v = fmaxf((acc[nt][r] - mu) * rstd * gm[nt] + bt[nt], 0.0f);
            lt[wid][lrow * 136 + nt * 16 + fr] = f2b(v);
        }
    }

    // coalesced store: 16 rows x 128 bf16, row stride 320 in a1
#pragma unroll
    for (int i = 0; i < 4; i++) {
        const int chunk = i * 64 + lane;
        const int row = chunk >> 4, seg = chunk & 15;
        if (m0 + row < n_nodes) {
            us8 v = *reinterpret_cast<const us8*>(&lt[wid][row * 136 + seg * 8]);
            *reinterpret_cast<us8*>(Yout + (size_t)(m0 + row) * 320 + seg * 8) = v;
        }
    }
}

// conv1: out = relu(LN(a1 @ wt1^T + b1 + b_lin)); f32 out [n][128]
__global__ __launch_bounds__(256) void conv1_mfma(
    const unsigned short* __restrict__ A,  // a1 [npad][320]
    const unsigned short* __restrict__ Wt, // [128][320]
    const float* __restrict__ b1, const float* __restrict__ bl,
    const float* __restrict__ gamma, const float* __restrict__ beta,
    float* __restrict__ Out, int n_nodes)
{
    __shared__ float lt[4][16 * 132];
    const int wid = threadIdx.x >> 6;
    const int lane = threadIdx.x & 63;
    const int m0 = blockIdx.x * 64 + wid * 16;
    if (m0 >= n_nodes) return;
    const int g = lane >> 4, fr = lane & 15;

    f32x4 acc[8];
    float gm[8], bt[8];
#pragma unroll
    for (int nt = 0; nt < 8; nt++) {
        const int col = nt * 16 + fr;
        const float bb = b1[col] + bl[col];
        acc[nt] = (f32x4){bb, bb, bb, bb};
        gm[nt] = gamma[col]; bt[nt] = beta[col];
    }

    const bf16x8* Ap = reinterpret_cast<const bf16x8*>(A + (size_t)(m0 + fr) * 320) + g;
    const bf16x8* Wp = reinterpret_cast<const bf16x8*>(Wt + (size_t)fr * 320) + g;
#pragma unroll
    for (int ks = 0; ks < 10; ks++) {
        const bf16x8 a = Ap[ks * 4];
#pragma unroll
        for (int nt = 0; nt < 8; nt++) {
            const bf16x8 w = Wp[nt * 16 * 40 + ks * 4];   // nt*16 rows * (320/8)
            acc[nt] = __builtin_amdgcn_mfma_f32_16x16x32_bf16(a, w, acc[nt], 0, 0, 0);
        }
    }

#pragma unroll
    for (int r = 0; r < 4; r++) {
        float s = 0.f, s2 = 0.f;
#pragma unroll
        for (int nt = 0; nt < 8; nt++) { const float v = acc[nt][r]; s += v; s2 += v * v; }
#pragma unroll
        for (int off = 1; off < 16; off <<= 1) {
            s += __shfl_xor(s, off); s2 += __shfl_xor(s2, off);
        }
        const float mu = s * (1.0f / COUT);
        const float var = s2 * (1.0f / COUT) - mu * mu;
        const float rstd = rsqrtf(var + LN_EPS);
        const int lrow = g * 4 + r;
#pragma unroll
        for (int nt = 0; nt < 8; nt++) {
            const float v = fmaxf((acc[nt][r] - mu) * rstd * gm[nt] + bt[nt], 0.0f);
            lt[wid][lrow * 132 + nt * 16 + fr] = v;
        }
    }

#pragma unroll
    for (int i = 0; i < 8; i++) {
        const int chunk = i * 64 + lane;
        const int row = chunk >> 5, seg = chunk & 31;
        if (m0 + row < n_nodes) {
            f32x4 v = *reinterpret_cast<const f32x4*>(&lt[wid][row * 132 + seg * 4]);
            *reinterpret_cast<f32x4*>(Out + (size_t)(m0 + row) * 128 + seg * 4) = v;
        }
    }
}

extern "C" void kernel_launch(void* const* d_in, const int* in_sizes, int n_in,
                              void* d_out, int out_size, void* d_ws, size_t ws_size,
                              hipStream_t stream)
{
    const float* x       = (const float*)d_in[0];
    const int*   ei      = (const int*)d_in[1];
    const float* w_root0 = (const float*)d_in[2];
    const float* w_nbr0  = (const float*)d_in[3];
    const float* b0      = (const float*)d_in[4];
    const float* w_root1 = (const float*)d_in[5];
    const float* w_nbr1  = (const float*)d_in[6];
    const float* b1      = (const float*)d_in[7];
    const float* gamma0  = (const float*)d_in[8];
    const float* beta0   = (const float*)d_in[9];
    const float* gamma1  = (const float*)d_in[10];
    const float* beta1   = (const float*)d_in[11];
    const float* w_lin   = (const float*)d_in[12];
    const float* b_lin   = (const float*)d_in[13];
    float* out = (float*)d_out;

    const int n_nodes = in_sizes[0] / CIN;   // 100000
    const int n_edges = in_sizes[1] / 2;     // 1600000
    const int* src = ei;
    const int* dst = ei + n_edges;
    const int npad = (n_nodes + 63) & ~63;

    // ---- workspace layout (bytes) ----
    char* ws = (char*)d_ws;
    unsigned short* ab0 = (unsigned short*)ws;                       // npad*128 bf16
    unsigned short* a1  = ab0 + (size_t)npad * 128;                  // npad*320 bf16
    unsigned short* wt0 = a1 + (size_t)npad * 320;                   // 128*128
    unsigned short* wt1 = wt0 + 128 * 128;                           // 128*320
    int* rowptr  = (int*)(wt1 + 128 * 320);                          // n+1
    int* cursor  = rowptr + (n_nodes + 1);
    int* csum    = cursor + n_nodes;
    int* coff    = csum + SCANB;
    int* esorted = coff + SCANB;                                     // n_edges

    const int nchunks = (n_nodes + SCANB - 1) / SCANB;
    const int eblk = (n_edges + 255) / 256;
    const int nblk64 = npad / 64;

    // ---- prep (weights + x conversion) ----
    prep_weights<<<(128 * 128 + 128 * 320 + 255) / 256, 256, 0, stream>>>(
        w_root0, w_nbr0, w_root1, w_nbr1, w_lin, wt0, wt1);
    convert_x<<<(n_nodes * 16 + 255) / 256, 256, 0, stream>>>(x, ab0, a1, n_nodes);

    // ---- CSR build ----
    hipMemsetAsync(cursor, 0, (size_t)n_nodes * sizeof(int), stream);
    hist_kernel<<<eblk, 256, 0, stream>>>(dst, cursor, n_edges);
    scan1_kernel<<<nchunks, SCANB, 0, stream>>>(cursor, rowptr, csum, n_nodes);
    scan2_kernel<<<1, SCANB, 0, stream>>>(csum, coff, nchunks);
    scan3_kernel<<<nchunks, SCANB, 0, stream>>>(rowptr, coff, n_nodes, n_edges);
    hipMemcpyAsync(cursor, rowptr, (size_t)n_nodes * sizeof(int),
                   hipMemcpyDeviceToDevice, stream);
    fill_kernel<<<eblk, 256, 0, stream>>>(src, dst, cursor, esorted, n_edges);

    // ---- GraphConv 0 ----
    gather_c64<<<(n_nodes + 3) / 4, 256, 0, stream>>>(ab0, rowptr, esorted, n_nodes);
    conv0_mfma<<<nblk64, 256, 0, stream>>>(ab0, wt0, b0, gamma0, beta0, a1, n_nodes);

    // ---- GraphConv 1 + residual ----
    gather_c128<<<(n_nodes + 3) / 4, 256, 0, stream>>>(a1, rowptr, esorted, n_nodes);
    conv1_mfma<<<nblk64, 256, 0, stream>>>(a1, wt1, b1, b_lin, gamma1, beta1, out, n_nodes);
}

// Round 4
// 377.926 us; speedup vs baseline: 11.7203x; 1.3838x over previous
//
#include <hip/hip_runtime.h>

#define CIN 64
#define COUT 128
constexpr float LN_EPS = 1e-5f;

typedef __attribute__((ext_vector_type(8))) short    bf16x8;
typedef __attribute__((ext_vector_type(4))) float    f32x4;
typedef __attribute__((ext_vector_type(8))) unsigned short us8;

__device__ inline float b2f(unsigned short u) {
    union { unsigned int i; float f; } v; v.i = ((unsigned int)u) << 16; return v.f;
}
__device__ inline unsigned short f2b(float f) {
    union { float f; unsigned int i; } v; v.f = f;
    unsigned int x = v.i;
    return (unsigned short)((x + 0x7FFFu + ((x >> 16) & 1u)) >> 16);
}

// ================= linked-list build (replaces hist+scan+fill) =================
// head[d] = last edge id with dst==d; nxt[e] = previous edge id with same dst.
__global__ __launch_bounds__(256) void build_list(
    const int* __restrict__ dst, int* __restrict__ head,
    int* __restrict__ nxt, int n_edges)
{
    int e = blockIdx.x * 256 + threadIdx.x;
    if (e >= n_edges) return;
    nxt[e] = atomicExch(&head[dst[e]], e);   // coalesced write, 1 atomic/edge
}

// ================= prep: weights -> bf16 transposed, x -> bf16 =================

__global__ __launch_bounds__(256) void prep_weights(
    const float* __restrict__ wr0, const float* __restrict__ wn0,
    const float* __restrict__ wr1, const float* __restrict__ wn1,
    const float* __restrict__ wl,
    unsigned short* __restrict__ wt0, unsigned short* __restrict__ wt1)
{
    int t = blockIdx.x * blockDim.x + threadIdx.x;
    if (t < 128 * 128) {
        int n = t >> 7, k = t & 127;
        float v = (k < 64) ? wr0[k * COUT + n] : wn0[(k - 64) * COUT + n];
        wt0[n * 128 + k] = f2b(v);
    } else {
        int t2 = t - 128 * 128;
        if (t2 >= 128 * 320) return;
        int n = t2 / 320, k = t2 % 320;
        float v;
        if (k < 128)      v = wr1[k * COUT + n];
        else if (k < 256) v = wn1[(k - 128) * COUT + n];
        else              v = wl[(k - 256) * COUT + n];
        wt1[n * 320 + k] = f2b(v);
    }
}

__global__ __launch_bounds__(256) void convert_x(
    const float* __restrict__ x, unsigned short* __restrict__ ab0,
    unsigned short* __restrict__ a1, int n_nodes)
{
    int t = blockIdx.x * blockDim.x + threadIdx.x;
    int node = t >> 4;
    if (node >= n_nodes) return;
    int c = (t & 15) << 2;
    const float4 v = *reinterpret_cast<const float4*>(x + (size_t)node * CIN + c);
    unsigned int lo = (unsigned int)f2b(v.x) | ((unsigned int)f2b(v.y) << 16);
    unsigned int hi = (unsigned int)f2b(v.z) | ((unsigned int)f2b(v.w) << 16);
    unsigned int* p0 = (unsigned int*)(ab0 + (size_t)node * 128 + c);
    p0[0] = lo; p0[1] = hi;
    unsigned int* p1 = (unsigned int*)(a1 + (size_t)node * 320 + 256 + c);
    p1[0] = lo; p1[1] = hi;
}

// ================= gathers: chase linked list, 16-lane group per node =================

// agg over x rows (64 ch); lane fr covers 4 channels (8B load per hop)
__global__ __launch_bounds__(256) void gather_c64(
    unsigned short* __restrict__ ab0, const int* __restrict__ head,
    const int* __restrict__ nxt, const int* __restrict__ srcA, int n_nodes)
{
    const int node = blockIdx.x * 16 + (threadIdx.x >> 4);
    if (node >= n_nodes) return;
    const int fr = threadIdx.x & 15;
    float a0 = 0.f, a1v = 0.f, a2 = 0.f, a3 = 0.f;
    int e = head[node];
    if (e >= 0) {
        int s = srcA[e];
        int nx = nxt[e];
        while (true) {
            const unsigned long long u =
                *(const unsigned long long*)(ab0 + (size_t)s * 128 + fr * 4);
            const bool more = (nx >= 0);
            int s2 = 0, nx2 = 0;
            if (more) { s2 = srcA[nx]; nx2 = nxt[nx]; }   // prefetch next hop
            a0  += b2f((unsigned short)u);
            a1v += b2f((unsigned short)(u >> 16));
            a2  += b2f((unsigned short)(u >> 32));
            a3  += b2f((unsigned short)(u >> 48));
            if (!more) break;
            s = s2; nx = nx2;
        }
    }
    const unsigned long long p = (unsigned long long)f2b(a0)
        | ((unsigned long long)f2b(a1v) << 16)
        | ((unsigned long long)f2b(a2)  << 32)
        | ((unsigned long long)f2b(a3)  << 48);
    *(unsigned long long*)(ab0 + (size_t)node * 128 + 64 + fr * 4) = p;
}

// agg over y rows (128 ch, stride 320); lane fr covers 8 channels (16B load per hop)
__global__ __launch_bounds__(256) void gather_c128(
    unsigned short* __restrict__ a1, const int* __restrict__ head,
    const int* __restrict__ nxt, const int* __restrict__ srcA, int n_nodes)
{
    const int node = blockIdx.x * 16 + (threadIdx.x >> 4);
    if (node >= n_nodes) return;
    const int fr = threadIdx.x & 15;
    float acc[8] = {0.f, 0.f, 0.f, 0.f, 0.f, 0.f, 0.f, 0.f};
    int e = head[node];
    if (e >= 0) {
        int s = srcA[e];
        int nx = nxt[e];
        while (true) {
            const us8 row = *(const us8*)(a1 + (size_t)s * 320 + fr * 8);
            const bool more = (nx >= 0);
            int s2 = 0, nx2 = 0;
            if (more) { s2 = srcA[nx]; nx2 = nxt[nx]; }
#pragma unroll
            for (int j = 0; j < 8; j++) acc[j] += b2f(row[j]);
            if (!more) break;
            s = s2; nx = nx2;
        }
    }
    us8 p;
#pragma unroll
    for (int j = 0; j < 8; j++) p[j] = f2b(acc[j]);
    *(us8*)(a1 + (size_t)node * 320 + 128 + fr * 8) = p;
}

// ================= MFMA convs =================
// D[m][n]: col = lane&15, row = (lane>>4)*4 + reg  (m89-verified)

__global__ __launch_bounds__(256) void conv0_mfma(
    const unsigned short* __restrict__ A,  // ab0 [npad][128]
    const unsigned short* __restrict__ Wt, // [128][128]
    const float* __restrict__ b, const float* __restrict__ gamma,
    const float* __restrict__ beta,
    unsigned short* __restrict__ Yout,     // a1 base
    int n_nodes)
{
    __shared__ unsigned short lt[4][16 * 136];
    const int wid = threadIdx.x >> 6;
    const int lane = threadIdx.x & 63;
    const int m0 = blockIdx.x * 64 + wid * 16;
    if (m0 >= n_nodes) return;
    const int g = lane >> 4, fr = lane & 15;

    f32x4 acc[8];
    float gm[8], bt[8];
#pragma unroll
    for (int nt = 0; nt < 8; nt++) {
        const int col = nt * 16 + fr;
        const float bb = b[col];
        acc[nt] = (f32x4){bb, bb, bb, bb};
        gm[nt] = gamma[col]; bt[nt] = beta[col];
    }

    const bf16x8* Ap = reinterpret_cast<const bf16x8*>(A + (size_t)(m0 + fr) * 128) + g;
    const bf16x8* Wp = reinterpret_cast<const bf16x8*>(Wt + (size_t)fr * 128) + g;
#pragma unroll
    for (int ks = 0; ks < 4; ks++) {
        const bf16x8 a = Ap[ks * 4];
#pragma unroll
        for (int nt = 0; nt < 8; nt++) {
            const bf16x8 w = Wp[nt * 16 * 16 + ks * 4];
            acc[nt] = __builtin_amdgcn_mfma_f32_16x16x32_bf16(a, w, acc[nt], 0, 0, 0);
        }
    }

#pragma unroll
    for (int r = 0; r < 4; r++) {
        float s = 0.f, s2 = 0.f;
#pragma unroll
        for (int nt = 0; nt < 8; nt++) { const float v = acc[nt][r]; s += v; s2 += v * v; }
#pragma unroll
        for (int off = 1; off < 16; off <<= 1) {
            s += __shfl_xor(s, off); s2 += __shfl_xor(s2, off);
        }
        const float mu = s * (1.0f / COUT);
        const float var = s2 * (1.0f / COUT) - mu * mu;
        const float rstd = rsqrtf(var + LN_EPS);
        const int lrow = g * 4 + r;
#pragma unroll
        for (int nt = 0; nt < 8; nt++) {
            const float v = fmaxf((acc[nt][r] - mu) * rstd * gm[nt] + bt[nt], 0.0f);
            lt[wid][lrow * 136 + nt * 16 + fr] = f2b(v);
        }
    }

#pragma unroll
    for (int i = 0; i < 4; i++) {
        const int chunk = i * 64 + lane;
        const int row = chunk >> 4, seg = chunk & 15;
        if (m0 + row < n_nodes) {
            us8 v = *reinterpret_cast<const us8*>(&lt[wid][row * 136 + seg * 8]);
            *reinterpret_cast<us8*>(Yout + (size_t)(m0 + row) * 320 + seg * 8) = v;
        }
    }
}

__global__ __launch_bounds__(256) void conv1_mfma(
    const unsigned short* __restrict__ A,  // a1 [npad][320]
    const unsigned short* __restrict__ Wt, // [128][320]
    const float* __restrict__ b1, const float* __restrict__ bl,
    const float* __restrict__ gamma, const float* __restrict__ beta,
    float* __restrict__ Out, int n_nodes)
{
    __shared__ float lt[4][16 * 132];
    const int wid = threadIdx.x >> 6;
    const int lane = threadIdx.x & 63;
    const int m0 = blockIdx.x * 64 + wid * 16;
    if (m0 >= n_nodes) return;
    const int g = lane >> 4, fr = lane & 15;

    f32x4 acc[8];
    float gm[8], bt[8];
#pragma unroll
    for (int nt = 0; nt < 8; nt++) {
        const int col = nt * 16 + fr;
        const float bb = b1[col] + bl[col];
        acc[nt] = (f32x4){bb, bb, bb, bb};
        gm[nt] = gamma[col]; bt[nt] = beta[col];
    }

    const bf16x8* Ap = reinterpret_cast<const bf16x8*>(A + (size_t)(m0 + fr) * 320) + g;
    const bf16x8* Wp = reinterpret_cast<const bf16x8*>(Wt + (size_t)fr * 320) + g;
#pragma unroll
    for (int ks = 0; ks < 10; ks++) {
        const bf16x8 a = Ap[ks * 4];
#pragma unroll
        for (int nt = 0; nt < 8; nt++) {
            const bf16x8 w = Wp[nt * 16 * 40 + ks * 4];
            acc[nt] = __builtin_amdgcn_mfma_f32_16x16x32_bf16(a, w, acc[nt], 0, 0, 0);
        }
    }

#pragma unroll
    for (int r = 0; r < 4; r++) {
        float s = 0.f, s2 = 0.f;
#pragma unroll
        for (int nt = 0; nt < 8; nt++) { const float v = acc[nt][r]; s += v; s2 += v * v; }
#pragma unroll
        for (int off = 1; off < 16; off <<= 1) {
            s += __shfl_xor(s, off); s2 += __shfl_xor(s2, off);
        }
        const float mu = s * (1.0f / COUT);
        const float var = s2 * (1.0f / COUT) - mu * mu;
        const float rstd = rsqrtf(var + LN_EPS);
        const int lrow = g * 4 + r;
#pragma unroll
        for (int nt = 0; nt < 8; nt++) {
            const float v = fmaxf((acc[nt][r] - mu) * rstd * gm[nt] + bt[nt], 0.0f);
            lt[wid][lrow * 132 + nt * 16 + fr] = v;
        }
    }

#pragma unroll
    for (int i = 0; i < 8; i++) {
        const int chunk = i * 64 + lane;
        const int row = chunk >> 5, seg = chunk & 31;
        if (m0 + row < n_nodes) {
            f32x4 v = *reinterpret_cast<const f32x4*>(&lt[wid][row * 132 + seg * 4]);
            *reinterpret_cast<f32x4*>(Out + (size_t)(m0 + row) * 128 + seg * 4) = v;
        }
    }
}

extern "C" void kernel_launch(void* const* d_in, const int* in_sizes, int n_in,
                              void* d_out, int out_size, void* d_ws, size_t ws_size,
                              hipStream_t stream)
{
    const float* x       = (const float*)d_in[0];
    const int*   ei      = (const int*)d_in[1];
    const float* w_root0 = (const float*)d_in[2];
    const float* w_nbr0  = (const float*)d_in[3];
    const float* b0      = (const float*)d_in[4];
    const float* w_root1 = (const float*)d_in[5];
    const float* w_nbr1  = (const float*)d_in[6];
    const float* b1      = (const float*)d_in[7];
    const float* gamma0  = (const float*)d_in[8];
    const float* beta0   = (const float*)d_in[9];
    const float* gamma1  = (const float*)d_in[10];
    const float* beta1   = (const float*)d_in[11];
    const float* w_lin   = (const float*)d_in[12];
    const float* b_lin   = (const float*)d_in[13];
    float* out = (float*)d_out;

    const int n_nodes = in_sizes[0] / CIN;   // 100000
    const int n_edges = in_sizes[1] / 2;     // 1600000
    const int* src = ei;
    const int* dst = ei + n_edges;
    const int npad = (n_nodes + 63) & ~63;

    // ---- workspace layout ----
    char* ws = (char*)d_ws;
    unsigned short* ab0 = (unsigned short*)ws;                       // npad*128 bf16
    unsigned short* a1  = ab0 + (size_t)npad * 128;                  // npad*320 bf16
    unsigned short* wt0 = a1 + (size_t)npad * 320;                   // 128*128
    unsigned short* wt1 = wt0 + 128 * 128;                           // 128*320
    int* head = (int*)(wt1 + 128 * 320);                             // n_nodes
    int* nxt  = head + n_nodes;                                      // n_edges

    const int eblk = (n_edges + 255) / 256;
    const int nblk64 = npad / 64;
    const int nblk16 = (n_nodes + 15) / 16;

    // ---- prep (weights + x conversion) ----
    prep_weights<<<(128 * 128 + 128 * 320 + 255) / 256, 256, 0, stream>>>(
        w_root0, w_nbr0, w_root1, w_nbr1, w_lin, wt0, wt1);
    convert_x<<<(n_nodes * 16 + 255) / 256, 256, 0, stream>>>(x, ab0, a1, n_nodes);

    // ---- linked-list build (once, reused by both gathers) ----
    hipMemsetAsync(head, 0xFF, (size_t)n_nodes * sizeof(int), stream);   // head = -1
    build_list<<<eblk, 256, 0, stream>>>(dst, head, nxt, n_edges);

    // ---- GraphConv 0 ----
    gather_c64<<<nblk16, 256, 0, stream>>>(ab0, head, nxt, src, n_nodes);
    conv0_mfma<<<nblk64, 256, 0, stream>>>(ab0, wt0, b0, gamma0, beta0, a1, n_nodes);

    // ---- GraphConv 1 + residual ----
    gather_c128<<<nblk16, 256, 0, stream>>>(a1, head, nxt, src, n_nodes);
    conv1_mfma<<<nblk64, 256, 0, stream>>>(a1, wt1, b1, b_lin, gamma1, beta1, out, n_nodes);
}

// Round 5
// 335.812 us; speedup vs baseline: 13.1901x; 1.1254x over previous
//
#include <hip/hip_runtime.h>

#define CIN 64
#define COUT 128
constexpr float LN_EPS = 1e-5f;

typedef __attribute__((ext_vector_type(8))) short    bf16x8;
typedef __attribute__((ext_vector_type(4))) float    f32x4;
typedef __attribute__((ext_vector_type(8))) unsigned short us8;

__device__ inline float b2f(unsigned short u) {
    union { unsigned int i; float f; } v; v.i = ((unsigned int)u) << 16; return v.f;
}
__device__ inline unsigned short f2b(float f) {
    union { float f; unsigned int i; } v; v.f = f;
    unsigned int x = v.i;
    return (unsigned short)((x + 0x7FFFu + ((x >> 16) & 1u)) >> 16);
}

// ============ fused prep: linked-list build | x->bf16 | weights->bf16^T ============
// head[d] = last edge id with dst==d; nxs[e] = (src[e], previous edge with same dst)
__global__ __launch_bounds__(256) void fused_prep(
    const int* __restrict__ src, const int* __restrict__ dst,
    const float* __restrict__ x,
    const float* __restrict__ wr0, const float* __restrict__ wn0,
    const float* __restrict__ wr1, const float* __restrict__ wn1,
    const float* __restrict__ wl,
    int* __restrict__ head, int2* __restrict__ nxs,
    unsigned short* __restrict__ ab0, unsigned short* __restrict__ a1,
    unsigned short* __restrict__ wt0, unsigned short* __restrict__ wt1,
    int n_nodes, int n_edges, int eblk, int cblk)
{
    const int bid = blockIdx.x;
    if (bid < eblk) {
        // ---- linked-list build ----
        int e = bid * 256 + threadIdx.x;
        if (e >= n_edges) return;
        int s = src[e];
        int prev = atomicExch(&head[dst[e]], e);
        nxs[e] = make_int2(s, prev);            // coalesced 8B write
    } else if (bid < eblk + cblk) {
        // ---- x (f32) -> ab0[:,0:64] and a1[:,256:320] bf16 ----
        int t = (bid - eblk) * 256 + threadIdx.x;
        int node = t >> 4;
        if (node >= n_nodes) return;
        int c = (t & 15) << 2;
        const float4 v = *reinterpret_cast<const float4*>(x + (size_t)node * CIN + c);
        unsigned int lo = (unsigned int)f2b(v.x) | ((unsigned int)f2b(v.y) << 16);
        unsigned int hi = (unsigned int)f2b(v.z) | ((unsigned int)f2b(v.w) << 16);
        unsigned int* p0 = (unsigned int*)(ab0 + (size_t)node * 128 + c);
        p0[0] = lo; p0[1] = hi;
        unsigned int* p1 = (unsigned int*)(a1 + (size_t)node * 320 + 256 + c);
        p1[0] = lo; p1[1] = hi;
    } else {
        // ---- weights -> bf16 transposed ----
        int t = (bid - eblk - cblk) * 256 + threadIdx.x;
        if (t < 128 * 128) {
            int n = t >> 7, k = t & 127;
            float v = (k < 64) ? wr0[k * COUT + n] : wn0[(k - 64) * COUT + n];
            wt0[n * 128 + k] = f2b(v);
        } else {
            int t2 = t - 128 * 128;
            if (t2 >= 128 * 320) return;
            int n = t2 / 320, k = t2 % 320;
            float v;
            if (k < 128)      v = wr1[k * COUT + n];
            else if (k < 256) v = wn1[(k - 128) * COUT + n];
            else              v = wl[(k - 256) * COUT + n];
            wt1[n * 320 + k] = f2b(v);
        }
    }
}

// ================= gathers: chase packed linked list =================

// agg over x rows (64 ch); 16-lane group per node, lane = 4 ch (8B/hop)
__global__ __launch_bounds__(256) void gather_c64(
    unsigned short* __restrict__ ab0, const int* __restrict__ head,
    const int2* __restrict__ nxs, int n_nodes)
{
    const int node = blockIdx.x * 16 + (threadIdx.x >> 4);
    if (node >= n_nodes) return;
    const int fr = threadIdx.x & 15;
    float a0 = 0.f, a1v = 0.f, a2 = 0.f, a3 = 0.f;
    int e = head[node];
    if (e >= 0) {
        int2 sn = nxs[e];
        while (true) {
            const unsigned long long u =
                *(const unsigned long long*)(ab0 + (size_t)sn.x * 128 + fr * 4);
            const bool more = (sn.y >= 0);
            int2 sn2;
            if (more) sn2 = nxs[sn.y];           // prefetch next hop (1 line)
            a0  += b2f((unsigned short)u);
            a1v += b2f((unsigned short)(u >> 16));
            a2  += b2f((unsigned short)(u >> 32));
            a3  += b2f((unsigned short)(u >> 48));
            if (!more) break;
            sn = sn2;
        }
    }
    const unsigned long long p = (unsigned long long)f2b(a0)
        | ((unsigned long long)f2b(a1v) << 16)
        | ((unsigned long long)f2b(a2)  << 32)
        | ((unsigned long long)f2b(a3)  << 48);
    *(unsigned long long*)(ab0 + (size_t)node * 128 + 64 + fr * 4) = p;
}

// agg over y rows (128 ch, stride 320); 16-lane group per node, lane = 8 ch (16B/hop)
__global__ __launch_bounds__(256) void gather_c128(
    unsigned short* __restrict__ a1, const int* __restrict__ head,
    const int2* __restrict__ nxs, int n_nodes)
{
    const int node = blockIdx.x * 16 + (threadIdx.x >> 4);
    if (node >= n_nodes) return;
    const int fr = threadIdx.x & 15;
    float acc[8] = {0.f, 0.f, 0.f, 0.f, 0.f, 0.f, 0.f, 0.f};
    int e = head[node];
    if (e >= 0) {
        int2 sn = nxs[e];
        while (true) {
            const us8 row = *(const us8*)(a1 + (size_t)sn.x * 320 + fr * 8);
            const bool more = (sn.y >= 0);
            int2 sn2;
            if (more) sn2 = nxs[sn.y];
#pragma unroll
            for (int j = 0; j < 8; j++) acc[j] += b2f(row[j]);
            if (!more) break;
            sn = sn2;
        }
    }
    us8 p;
#pragma unroll
    for (int j = 0; j < 8; j++) p[j] = f2b(acc[j]);
    *(us8*)(a1 + (size_t)node * 320 + 128 + fr * 8) = p;
}

// ================= MFMA convs =================
// D[m][n]: col = lane&15, row = (lane>>4)*4 + reg  (m89-verified)

__global__ __launch_bounds__(256) void conv0_mfma(
    const unsigned short* __restrict__ A,  // ab0 [npad][128]
    const unsigned short* __restrict__ Wt, // [128][128]
    const float* __restrict__ b, const float* __restrict__ gamma,
    const float* __restrict__ beta,
    unsigned short* __restrict__ Yout,     // a1 base
    int n_nodes)
{
    __shared__ unsigned short lt[4][16 * 136];
    const int wid = threadIdx.x >> 6;
    const int lane = threadIdx.x & 63;
    const int m0 = blockIdx.x * 64 + wid * 16;
    if (m0 >= n_nodes) return;
    const int g = lane >> 4, fr = lane & 15;

    f32x4 acc[8];
    float gm[8], bt[8];
#pragma unroll
    for (int nt = 0; nt < 8; nt++) {
        const int col = nt * 16 + fr;
        const float bb = b[col];
        acc[nt] = (f32x4){bb, bb, bb, bb};
        gm[nt] = gamma[col]; bt[nt] = beta[col];
    }

    const bf16x8* Ap = reinterpret_cast<const bf16x8*>(A + (size_t)(m0 + fr) * 128) + g;
    const bf16x8* Wp = reinterpret_cast<const bf16x8*>(Wt + (size_t)fr * 128) + g;
#pragma unroll
    for (int ks = 0; ks < 4; ks++) {
        const bf16x8 a = Ap[ks * 4];
#pragma unroll
        for (int nt = 0; nt < 8; nt++) {
            const bf16x8 w = Wp[nt * 16 * 16 + ks * 4];
            acc[nt] = __builtin_amdgcn_mfma_f32_16x16x32_bf16(a, w, acc[nt], 0, 0, 0);
        }
    }

#pragma unroll
    for (int r = 0; r < 4; r++) {
        float s = 0.f, s2 = 0.f;
#pragma unroll
        for (int nt = 0; nt < 8; nt++) { const float v = acc[nt][r]; s += v; s2 += v * v; }
#pragma unroll
        for (int off = 1; off < 16; off <<= 1) {
            s += __shfl_xor(s, off); s2 += __shfl_xor(s2, off);
        }
        const float mu = s * (1.0f / COUT);
        const float var = s2 * (1.0f / COUT) - mu * mu;
        const float rstd = rsqrtf(var + LN_EPS);
        const int lrow = g * 4 + r;
#pragma unroll
        for (int nt = 0; nt < 8; nt++) {
            const float v = fmaxf((acc[nt][r] - mu) * rstd * gm[nt] + bt[nt], 0.0f);
            lt[wid][lrow * 136 + nt * 16 + fr] = f2b(v);
        }
    }

#pragma unroll
    for (int i = 0; i < 4; i++) {
        const int chunk = i * 64 + lane;
        const int row = chunk >> 4, seg = chunk & 15;
        if (m0 + row < n_nodes) {
            us8 v = *reinterpret_cast<const us8*>(&lt[wid][row * 136 + seg * 8]);
            *reinterpret_cast<us8*>(Yout + (size_t)(m0 + row) * 320 + seg * 8) = v;
        }
    }
}

__global__ __launch_bounds__(256) void conv1_mfma(
    const unsigned short* __restrict__ A,  // a1 [npad][320]
    const unsigned short* __restrict__ Wt, // [128][320]
    const float* __restrict__ b1, const float* __restrict__ bl,
    const float* __restrict__ gamma, const float* __restrict__ beta,
    float* __restrict__ Out, int n_nodes)
{
    __shared__ float lt[4][16 * 132];
    const int wid = threadIdx.x >> 6;
    const int lane = threadIdx.x & 63;
    const int m0 = blockIdx.x * 64 + wid * 16;
    if (m0 >= n_nodes) return;
    const int g = lane >> 4, fr = lane & 15;

    f32x4 acc[8];
    float gm[8], bt[8];
#pragma unroll
    for (int nt = 0; nt < 8; nt++) {
        const int col = nt * 16 + fr;
        const float bb = b1[col] + bl[col];
        acc[nt] = (f32x4){bb, bb, bb, bb};
        gm[nt] = gamma[col]; bt[nt] = beta[col];
    }

    const bf16x8* Ap = reinterpret_cast<const bf16x8*>(A + (size_t)(m0 + fr) * 320) + g;
    const bf16x8* Wp = reinterpret_cast<const bf16x8*>(Wt + (size_t)fr * 320) + g;
#pragma unroll
    for (int ks = 0; ks < 10; ks++) {
        const bf16x8 a = Ap[ks * 4];
#pragma unroll
        for (int nt = 0; nt < 8; nt++) {
            const bf16x8 w = Wp[nt * 16 * 40 + ks * 4];
            acc[nt] = __builtin_amdgcn_mfma_f32_16x16x32_bf16(a, w, acc[nt], 0, 0, 0);
        }
    }

#pragma unroll
    for (int r = 0; r < 4; r++) {
        float s = 0.f, s2 = 0.f;
#pragma unroll
        for (int nt = 0; nt < 8; nt++) { const float v = acc[nt][r]; s += v; s2 += v * v; }
#pragma unroll
        for (int off = 1; off < 16; off <<= 1) {
            s += __shfl_xor(s, off); s2 += __shfl_xor(s2, off);
        }
        const float mu = s * (1.0f / COUT);
        const float var = s2 * (1.0f / COUT) - mu * mu;
        const float rstd = rsqrtf(var + LN_EPS);
        const int lrow = g * 4 + r;
#pragma unroll
        for (int nt = 0; nt < 8; nt++) {
            const float v = fmaxf((acc[nt][r] - mu) * rstd * gm[nt] + bt[nt], 0.0f);
            lt[wid][lrow * 132 + nt * 16 + fr] = v;
        }
    }

#pragma unroll
    for (int i = 0; i < 8; i++) {
        const int chunk = i * 64 + lane;
        const int row = chunk >> 5, seg = chunk & 31;
        if (m0 + row < n_nodes) {
            f32x4 v = *reinterpret_cast<const f32x4*>(&lt[wid][row * 132 + seg * 4]);
            __builtin_nontemporal_store(
                v, reinterpret_cast<f32x4*>(Out + (size_t)(m0 + row) * 128 + seg * 4));
        }
    }
}

extern "C" void kernel_launch(void* const* d_in, const int* in_sizes, int n_in,
                              void* d_out, int out_size, void* d_ws, size_t ws_size,
                              hipStream_t stream)
{
    const float* x       = (const float*)d_in[0];
    const int*   ei      = (const int*)d_in[1];
    const float* w_root0 = (const float*)d_in[2];
    const float* w_nbr0  = (const float*)d_in[3];
    const float* b0      = (const float*)d_in[4];
    const float* w_root1 = (const float*)d_in[5];
    const float* w_nbr1  = (const float*)d_in[6];
    const float* b1      = (const float*)d_in[7];
    const float* gamma0  = (const float*)d_in[8];
    const float* beta0   = (const float*)d_in[9];
    const float* gamma1  = (const float*)d_in[10];
    const float* beta1   = (const float*)d_in[11];
    const float* w_lin   = (const float*)d_in[12];
    const float* b_lin   = (const float*)d_in[13];
    float* out = (float*)d_out;

    const int n_nodes = in_sizes[0] / CIN;   // 100000
    const int n_edges = in_sizes[1] / 2;     // 1600000
    const int* src = ei;
    const int* dst = ei + n_edges;
    const int npad = (n_nodes + 63) & ~63;

    // ---- workspace layout ----
    char* ws = (char*)d_ws;
    unsigned short* ab0 = (unsigned short*)ws;                       // npad*128 bf16
    unsigned short* a1  = ab0 + (size_t)npad * 128;                  // npad*320 bf16
    unsigned short* wt0 = a1 + (size_t)npad * 320;                   // 128*128
    unsigned short* wt1 = wt0 + 128 * 128;                           // 128*320
    int*  head = (int*)(wt1 + 128 * 320);                            // n_nodes
    int2* nxs  = (int2*)((char*)(head + n_nodes + 2) +
                         ((16 - (((size_t)(head + n_nodes + 2)) & 15)) & 15)); // n_edges int2

    const int eblk = (n_edges + 255) / 256;
    const int cblk = (n_nodes * 16 + 255) / 256;
    const int wblk = (128 * 128 + 128 * 320 + 255) / 256;
    const int nblk64 = npad / 64;
    const int nblk16 = (n_nodes + 15) / 16;

    // ---- prep: list build | x convert | weight convert (one fused kernel) ----
    hipMemsetAsync(head, 0xFF, (size_t)n_nodes * sizeof(int), stream);   // head = -1
    fused_prep<<<eblk + cblk + wblk, 256, 0, stream>>>(
        src, dst, x, w_root0, w_nbr0, w_root1, w_nbr1, w_lin,
        head, nxs, ab0, a1, wt0, wt1, n_nodes, n_edges, eblk, cblk);

    // ---- GraphConv 0 ----
    gather_c64<<<nblk16, 256, 0, stream>>>(ab0, head, nxs, n_nodes);
    conv0_mfma<<<nblk64, 256, 0, stream>>>(ab0, wt0, b0, gamma0, beta0, a1, n_nodes);

    // ---- GraphConv 1 + residual ----
    gather_c128<<<nblk16, 256, 0, stream>>>(a1, head, nxs, n_nodes);
    conv1_mfma<<<nblk64, 256, 0, stream>>>(a1, wt1, b1, b_lin, gamma1, beta1, out, n_nodes);
}

// Round 6
// 273.012 us; speedup vs baseline: 16.2241x; 1.2300x over previous
//
#include <hip/hip_runtime.h>

#define CIN 64
#define COUT 128
constexpr float LN_EPS = 1e-5f;

typedef __attribute__((ext_vector_type(8))) short    bf16x8;
typedef __attribute__((ext_vector_type(4))) float    f32x4;
typedef __attribute__((ext_vector_type(8))) unsigned short us8;

__device__ inline float b2f(unsigned short u) {
    union { unsigned int i; float f; } v; v.i = ((unsigned int)u) << 16; return v.f;
}
__device__ inline unsigned short f2b(float f) {
    union { float f; unsigned int i; } v; v.f = f;
    unsigned int x = v.i;
    return (unsigned short)((x + 0x7FFFu + ((x >> 16) & 1u)) >> 16);
}

// ============ fused prep: linked-list build | x->bf16 | weights->fragment-packed bf16 ============
// head[d] = last edge id with dst==d; nxs[e] = (src[e], previous edge with same dst)
// wp0: [nt(8)][ks(4)][lane(64)][j(8)]  frag el = W0t[nt*16+(lane&15)][ks*32+(lane>>4)*8+j]
// wp1: [nt(8)][ks(10)][lane(64)][j(8)] same with K=320 concat (wr1|wn1|wl)
__global__ __launch_bounds__(256) void fused_prep(
    const int* __restrict__ src, const int* __restrict__ dst,
    const float* __restrict__ x,
    const float* __restrict__ wr0, const float* __restrict__ wn0,
    const float* __restrict__ wr1, const float* __restrict__ wn1,
    const float* __restrict__ wl,
    int* __restrict__ head, int2* __restrict__ nxs,
    unsigned short* __restrict__ ab0, unsigned short* __restrict__ a1,
    unsigned short* __restrict__ wp0, unsigned short* __restrict__ wp1,
    int n_nodes, int n_edges, int eblk, int cblk)
{
    const int bid = blockIdx.x;
    if (bid < eblk) {
        // ---- linked-list build ----
        int e = bid * 256 + threadIdx.x;
        if (e >= n_edges) return;
        int s = src[e];
        int prev = atomicExch(&head[dst[e]], e);
        nxs[e] = make_int2(s, prev);            // coalesced 8B write
    } else if (bid < eblk + cblk) {
        // ---- x (f32) -> ab0[:,0:64] and a1[:,256:320] bf16 ----
        int t = (bid - eblk) * 256 + threadIdx.x;
        int node = t >> 4;
        if (node >= n_nodes) return;
        int c = (t & 15) << 2;
        const float4 v = *reinterpret_cast<const float4*>(x + (size_t)node * CIN + c);
        unsigned int lo = (unsigned int)f2b(v.x) | ((unsigned int)f2b(v.y) << 16);
        unsigned int hi = (unsigned int)f2b(v.z) | ((unsigned int)f2b(v.w) << 16);
        unsigned int* p0 = (unsigned int*)(ab0 + (size_t)node * 128 + c);
        p0[0] = lo; p0[1] = hi;
        unsigned int* p1 = (unsigned int*)(a1 + (size_t)node * 320 + 256 + c);
        p1[0] = lo; p1[1] = hi;
    } else {
        // ---- weights -> fragment-packed bf16 ----
        int t = (bid - eblk - cblk) * 256 + threadIdx.x;
        if (t < 8 * 4 * 64 * 8) {
            // wp0
            const int j = t & 7, idx = t >> 3;
            const int lane = idx & 63, fk = idx >> 6;      // fk = nt*4+ks
            const int nt = fk >> 2, ks = fk & 3;
            const int n = nt * 16 + (lane & 15);
            const int k = ks * 32 + (lane >> 4) * 8 + j;
            const float v = (k < 64) ? wr0[k * COUT + n] : wn0[(k - 64) * COUT + n];
            wp0[t] = f2b(v);
        } else {
            const int t2 = t - 8 * 4 * 64 * 8;
            if (t2 >= 8 * 10 * 64 * 8) return;
            const int j = t2 & 7, idx = t2 >> 3;
            const int lane = idx & 63, fk = idx >> 6;      // fk = nt*10+ks
            const int nt = fk / 10, ks = fk % 10;
            const int n = nt * 16 + (lane & 15);
            const int k = ks * 32 + (lane >> 4) * 8 + j;
            float v;
            if (k < 128)      v = wr1[k * COUT + n];
            else if (k < 256) v = wn1[(k - 128) * COUT + n];
            else              v = wl[(k - 256) * COUT + n];
            wp1[t2] = f2b(v);
        }
    }
}

// ================= gathers: chase packed linked list =================

// agg over x rows (64 ch); 16-lane group per node, lane = 4 ch (8B/hop)
__global__ __launch_bounds__(256) void gather_c64(
    unsigned short* __restrict__ ab0, const int* __restrict__ head,
    const int2* __restrict__ nxs, int n_nodes)
{
    const int node = blockIdx.x * 16 + (threadIdx.x >> 4);
    if (node >= n_nodes) return;
    const int fr = threadIdx.x & 15;
    float a0 = 0.f, a1v = 0.f, a2 = 0.f, a3 = 0.f;
    int e = head[node];
    if (e >= 0) {
        int2 sn = nxs[e];
        while (true) {
            const unsigned long long u =
                *(const unsigned long long*)(ab0 + (size_t)sn.x * 128 + fr * 4);
            const bool more = (sn.y >= 0);
            int2 sn2;
            if (more) sn2 = nxs[sn.y];           // prefetch next hop (1 line)
            a0  += b2f((unsigned short)u);
            a1v += b2f((unsigned short)(u >> 16));
            a2  += b2f((unsigned short)(u >> 32));
            a3  += b2f((unsigned short)(u >> 48));
            if (!more) break;
            sn = sn2;
        }
    }
    const unsigned long long p = (unsigned long long)f2b(a0)
        | ((unsigned long long)f2b(a1v) << 16)
        | ((unsigned long long)f2b(a2)  << 32)
        | ((unsigned long long)f2b(a3)  << 48);
    *(unsigned long long*)(ab0 + (size_t)node * 128 + 64 + fr * 4) = p;
}

// agg over y rows (128 ch, stride 320); 16-lane group per node, lane = 8 ch (16B/hop)
__global__ __launch_bounds__(256) void gather_c128(
    unsigned short* __restrict__ a1, const int* __restrict__ head,
    const int2* __restrict__ nxs, int n_nodes)
{
    const int node = blockIdx.x * 16 + (threadIdx.x >> 4);
    if (node >= n_nodes) return;
    const int fr = threadIdx.x & 15;
    float acc[8] = {0.f, 0.f, 0.f, 0.f, 0.f, 0.f, 0.f, 0.f};
    int e = head[node];
    if (e >= 0) {
        int2 sn = nxs[e];
        while (true) {
            const us8 row = *(const us8*)(a1 + (size_t)sn.x * 320 + fr * 8);
            const bool more = (sn.y >= 0);
            int2 sn2;
            if (more) sn2 = nxs[sn.y];
#pragma unroll
            for (int j = 0; j < 8; j++) acc[j] += b2f(row[j]);
            if (!more) break;
            sn = sn2;
        }
    }
    us8 p;
#pragma unroll
    for (int j = 0; j < 8; j++) p[j] = f2b(acc[j]);
    *(us8*)(a1 + (size_t)node * 320 + 128 + fr * 8) = p;
}

// ================= MFMA convs (fragment-packed W, preloaded A) =================
// D[m][n]: col = lane&15, row = (lane>>4)*4 + reg  (m89-verified)

__global__ __launch_bounds__(256) void conv0_mfma(
    const unsigned short* __restrict__ A,   // ab0 [npad][128]
    const unsigned short* __restrict__ Wpk, // wp0 [8][4][64][8]
    const float* __restrict__ b, const float* __restrict__ gamma,
    const float* __restrict__ beta,
    unsigned short* __restrict__ Yout,      // a1 base
    int n_nodes)
{
    __shared__ unsigned short lt[4][16 * 136];
    const int wid = threadIdx.x >> 6;
    const int lane = threadIdx.x & 63;
    const int m0 = blockIdx.x * 64 + wid * 16;
    if (m0 >= n_nodes) return;
    const int g = lane >> 4, fr = lane & 15;

    // preload all A-fragments (K=128 -> 4 frags, 16 VGPR)
    const bf16x8* Ap = reinterpret_cast<const bf16x8*>(A + (size_t)(m0 + fr) * 128) + g;
    bf16x8 a[4];
#pragma unroll
    for (int ks = 0; ks < 4; ks++) a[ks] = Ap[ks * 4];

    f32x4 acc[8];
    float gm[8], bt[8];
#pragma unroll
    for (int nt = 0; nt < 8; nt++) {
        const int col = nt * 16 + fr;
        const float bb = b[col];
        acc[nt] = (f32x4){bb, bb, bb, bb};
        gm[nt] = gamma[col]; bt[nt] = beta[col];
    }

    const bf16x8* Wp = reinterpret_cast<const bf16x8*>(Wpk) + lane;  // +64 per frag
#pragma unroll
    for (int nt = 0; nt < 8; nt++) {
        bf16x8 w[4];
#pragma unroll
        for (int ks = 0; ks < 4; ks++) w[ks] = Wp[(nt * 4 + ks) * 64];
#pragma unroll
        for (int ks = 0; ks < 4; ks++)
            acc[nt] = __builtin_amdgcn_mfma_f32_16x16x32_bf16(a[ks], w[ks], acc[nt], 0, 0, 0);
    }

#pragma unroll
    for (int r = 0; r < 4; r++) {
        float s = 0.f, s2 = 0.f;
#pragma unroll
        for (int nt = 0; nt < 8; nt++) { const float v = acc[nt][r]; s += v; s2 += v * v; }
#pragma unroll
        for (int off = 1; off < 16; off <<= 1) {
            s += __shfl_xor(s, off); s2 += __shfl_xor(s2, off);
        }
        const float mu = s * (1.0f / COUT);
        const float var = s2 * (1.0f / COUT) - mu * mu;
        const float rstd = rsqrtf(var + LN_EPS);
        const int lrow = g * 4 + r;
#pragma unroll
        for (int nt = 0; nt < 8; nt++) {
            const float v = fmaxf((acc[nt][r] - mu) * rstd * gm[nt] + bt[nt], 0.0f);
            lt[wid][lrow * 136 + nt * 16 + fr] = f2b(v);
        }
    }

#pragma unroll
    for (int i = 0; i < 4; i++) {
        const int chunk = i * 64 + lane;
        const int row = chunk >> 4, seg = chunk & 15;
        if (m0 + row < n_nodes) {
            us8 v = *reinterpret_cast<const us8*>(&lt[wid][row * 136 + seg * 8]);
            *reinterpret_cast<us8*>(Yout + (size_t)(m0 + row) * 320 + seg * 8) = v;
        }
    }
}

__global__ __launch_bounds__(256) void conv1_mfma(
    const unsigned short* __restrict__ A,   // a1 [npad][320]
    const unsigned short* __restrict__ Wpk, // wp1 [8][10][64][8]
    const float* __restrict__ b1, const float* __restrict__ bl,
    const float* __restrict__ gamma, const float* __restrict__ beta,
    float* __restrict__ Out, int n_nodes)
{
    __shared__ float lt[4][16 * 132];
    const int wid = threadIdx.x >> 6;
    const int lane = threadIdx.x & 63;
    const int m0 = blockIdx.x * 64 + wid * 16;
    if (m0 >= n_nodes) return;
    const int g = lane >> 4, fr = lane & 15;

    // preload all A-fragments (K=320 -> 10 frags, 40 VGPR)
    const bf16x8* Ap = reinterpret_cast<const bf16x8*>(A + (size_t)(m0 + fr) * 320) + g;
    bf16x8 a[10];
#pragma unroll
    for (int ks = 0; ks < 10; ks++) a[ks] = Ap[ks * 4];

    f32x4 acc[8];
    float gm[8], bt[8];
#pragma unroll
    for (int nt = 0; nt < 8; nt++) {
        const int col = nt * 16 + fr;
        const float bb = b1[col] + bl[col];
        acc[nt] = (f32x4){bb, bb, bb, bb};
        gm[nt] = gamma[col]; bt[nt] = beta[col];
    }

    const bf16x8* Wp = reinterpret_cast<const bf16x8*>(Wpk) + lane;  // +64 per frag
#pragma unroll
    for (int nt = 0; nt < 8; nt++) {
        bf16x8 w[10];
#pragma unroll
        for (int ks = 0; ks < 10; ks++) w[ks] = Wp[(nt * 10 + ks) * 64];
#pragma unroll
        for (int ks = 0; ks < 10; ks++)
            acc[nt] = __builtin_amdgcn_mfma_f32_16x16x32_bf16(a[ks], w[ks], acc[nt], 0, 0, 0);
    }

#pragma unroll
    for (int r = 0; r < 4; r++) {
        float s = 0.f, s2 = 0.f;
#pragma unroll
        for (int nt = 0; nt < 8; nt++) { const float v = acc[nt][r]; s += v; s2 += v * v; }
#pragma unroll
        for (int off = 1; off < 16; off <<= 1) {
            s += __shfl_xor(s, off); s2 += __shfl_xor(s2, off);
        }
        const float mu = s * (1.0f / COUT);
        const float var = s2 * (1.0f / COUT) - mu * mu;
        const float rstd = rsqrtf(var + LN_EPS);
        const int lrow = g * 4 + r;
#pragma unroll
        for (int nt = 0; nt < 8; nt++) {
            const float v = fmaxf((acc[nt][r] - mu) * rstd * gm[nt] + bt[nt], 0.0f);
            lt[wid][lrow * 132 + nt * 16 + fr] = v;
        }
    }

#pragma unroll
    for (int i = 0; i < 8; i++) {
        const int chunk = i * 64 + lane;
        const int row = chunk >> 5, seg = chunk & 31;
        if (m0 + row < n_nodes) {
            f32x4 v = *reinterpret_cast<const f32x4*>(&lt[wid][row * 132 + seg * 4]);
            __builtin_nontemporal_store(
                v, reinterpret_cast<f32x4*>(Out + (size_t)(m0 + row) * 128 + seg * 4));
        }
    }
}

extern "C" void kernel_launch(void* const* d_in, const int* in_sizes, int n_in,
                              void* d_out, int out_size, void* d_ws, size_t ws_size,
                              hipStream_t stream)
{
    const float* x       = (const float*)d_in[0];
    const int*   ei      = (const int*)d_in[1];
    const float* w_root0 = (const float*)d_in[2];
    const float* w_nbr0  = (const float*)d_in[3];
    const float* b0      = (const float*)d_in[4];
    const float* w_root1 = (const float*)d_in[5];
    const float* w_nbr1  = (const float*)d_in[6];
    const float* b1      = (const float*)d_in[7];
    const float* gamma0  = (const float*)d_in[8];
    const float* beta0   = (const float*)d_in[9];
    const float* gamma1  = (const float*)d_in[10];
    const float* beta1   = (const float*)d_in[11];
    const float* w_lin   = (const float*)d_in[12];
    const float* b_lin   = (const float*)d_in[13];
    float* out = (float*)d_out;

    const int n_nodes = in_sizes[0] / CIN;   // 100000
    const int n_edges = in_sizes[1] / 2;     // 1600000
    const int* src = ei;
    const int* dst = ei + n_edges;
    const int npad = (n_nodes + 63) & ~63;

    // ---- workspace layout ----
    char* ws = (char*)d_ws;
    unsigned short* ab0 = (unsigned short*)ws;                       // npad*128 bf16
    unsigned short* a1  = ab0 + (size_t)npad * 128;                  // npad*320 bf16
    unsigned short* wp0 = a1 + (size_t)npad * 320;                   // 8*4*64*8 = 16384
    unsigned short* wp1 = wp0 + 8 * 4 * 64 * 8;                      // 8*10*64*8 = 40960
    int*  head = (int*)(wp1 + 8 * 10 * 64 * 8);                      // n_nodes
    int2* nxs  = (int2*)((char*)(head + n_nodes + 2) +
                         ((16 - (((size_t)(head + n_nodes + 2)) & 15)) & 15)); // n_edges int2

    const int eblk = (n_edges + 255) / 256;
    const int cblk = (n_nodes * 16 + 255) / 256;
    const int wblk = (8 * 4 * 64 * 8 + 8 * 10 * 64 * 8 + 255) / 256;
    const int nblk64 = npad / 64;
    const int nblk16 = (n_nodes + 15) / 16;

    // ---- prep: list build | x convert | weight pack (one fused kernel) ----
    hipMemsetAsync(head, 0xFF, (size_t)n_nodes * sizeof(int), stream);   // head = -1
    fused_prep<<<eblk + cblk + wblk, 256, 0, stream>>>(
        src, dst, x, w_root0, w_nbr0, w_root1, w_nbr1, w_lin,
        head, nxs, ab0, a1, wp0, wp1, n_nodes, n_edges, eblk, cblk);

    // ---- GraphConv 0 ----
    gather_c64<<<nblk16, 256, 0, stream>>>(ab0, head, nxs, n_nodes);
    conv0_mfma<<<nblk64, 256, 0, stream>>>(ab0, wp0, b0, gamma0, beta0, a1, n_nodes);

    // ---- GraphConv 1 + residual ----
    gather_c128<<<nblk16, 256, 0, stream>>>(a1, head, nxs, n_nodes);
    conv1_mfma<<<nblk64, 256, 0, stream>>>(a1, wp1, b1, b_lin, gamma1, beta1, out, n_nodes);
}